// Round 5
// baseline (674.247 us; speedup 1.0000x reference)
//
#include <hip/hip_runtime.h>
#include <hip/hip_bf16.h>
#include <math.h>

typedef __hip_bfloat16 bf16;
typedef float f4 __attribute__((ext_vector_type(4)));
typedef short s8 __attribute__((ext_vector_type(8)));      // 8 bf16 fragment (4 VGPR)
typedef unsigned int u2 __attribute__((ext_vector_type(2)));
typedef unsigned int u4v __attribute__((ext_vector_type(4)));

// async global->LDS, 16B per lane; LDS dest = wave-uniform base + lane*16
__device__ __forceinline__ void gload16(const void* g, char* l) {
  __builtin_amdgcn_global_load_lds(
      (const __attribute__((address_space(1))) unsigned int*)g,
      (__attribute__((address_space(3))) unsigned int*)l, 16, 0, 0);
}
__device__ __forceinline__ unsigned short bfr(float f) {
  bf16 h = __float2bfloat16(f);
  return *(unsigned short*)&h;
}
__device__ __forceinline__ unsigned int pk2(float a, float b) {
  return (unsigned int)bfr(a) | ((unsigned int)bfr(b) << 16);
}
// truncating bf16x2 pack (lo=a, hi=b): 1 v_perm_b32
__device__ __forceinline__ unsigned int pkt(float a, float b) {
  return __builtin_amdgcn_perm(__float_as_uint(b), __float_as_uint(a), 0x07060302u);
}

// ---------------- weight prep: fp32 -> bf16 (+ w_c3 repack [m][tap][ic], + zero page)
__global__ __launch_bounds__(256) void prep_w(
    const float* __restrict__ wq, const float* __restrict__ wkv,
    const float* __restrict__ wo, const float* __restrict__ win,
    const float* __restrict__ wc3, const float* __restrict__ wc1,
    const float* __restrict__ wout, ushort* __restrict__ cw)
{
  int i = blockIdx.x * 256 + threadIdx.x;
  float v;
  if (i < 131072) v = wq[i];
  else if (i < 393216) v = wkv[i - 131072];
  else if (i < 524288) v = wo[i - 393216];
  else if (i < 557056) v = win[i - 524288];
  else if (i < 1146880) {
    int j = i - 557056; int lyr = j / 294912; int r = j - lyr * 294912;
    int m = r / 1152; int k = r - m * 1152; int tap = k >> 7; int ic = k & 127;
    v = wc3[(((size_t)lyr * 256 + m) * 128 + ic) * 9 + tap];
  }
  else if (i < 1212416) v = wc1[i - 1146880];
  else if (i < 1228800) v = wout[i - 1212416];
  else if (i < 1230848) { cw[i] = 0; return; }   // zero page
  else return;
  cw[i] = bfr(v);
}

// ---------------- LayerNorm over channels -> NHWC bf16. NCHW=true reads NCHW f32.
template<bool NCHW>
__global__ __launch_bounds__(256) void ln_nhwc(
    const float* __restrict__ x, const float* __restrict__ g,
    const float* __restrict__ b, ushort* __restrict__ y)
{
  const int p = blockIdx.x * 256 + threadIdx.x;
  f4 v[32];
  float s = 0.f, s2 = 0.f;
  if constexpr (NCHW) {
#pragma unroll
    for (int i = 0; i < 32; ++i)
#pragma unroll
      for (int j = 0; j < 4; ++j) {
        float t = x[(size_t)(i * 4 + j) * 65536 + p];
        v[i][j] = t; s += t; s2 += t * t;
      }
  } else {
    const f4* base = (const f4*)(x + (size_t)p * 128);
#pragma unroll
    for (int i = 0; i < 32; ++i) {
      v[i] = base[i];
#pragma unroll
      for (int j = 0; j < 4; ++j) { s += v[i][j]; s2 += v[i][j] * v[i][j]; }
    }
  }
  float mean = s * (1.f / 128.f);
  float var = s2 * (1.f / 128.f) - mean * mean;
  var = var > 0.f ? var : 0.f;
  float inv = 1.f / (sqrtf(var) + 1e-5f);
  u2* dst = (u2*)(y + (size_t)p * 128);
#pragma unroll
  for (int i = 0; i < 32; ++i) {
    f4 gg = *(const f4*)(g + i * 4);
    f4 bb = *(const f4*)(b + i * 4);
    float f0 = (v[i][0] - mean) * inv * gg[0] + bb[0];
    float f1 = (v[i][1] - mean) * inv * gg[1] + bb[1];
    float f2 = (v[i][2] - mean) * inv * gg[2] + bb[2];
    float f3 = (v[i][3] - mean) * inv * gg[3] + bb[3];
    u2 st; st.x = pk2(f0, f1); st.y = pk2(f2, f3);
    dst[i] = st;
  }
}

// ---------------- MFMA GEMM: C_nhwc[n][m] = sum_k A[m][k] * X[n][k]
// MODE 0: bf16 out + bias
// MODE 1: f32 out + bias + res(NHWC f32)
// MODE 2: NCHW f32 out + bias + res(NHWC f32)
// MODE 3: MODE 1 + bf16 mirror to out2
// MODE 4: f32 out + bias + res(NCHW f32)
template<int MODE>
__global__ __launch_bounds__(256) void gemm_nhwc(
    const ushort* __restrict__ A, const ushort* __restrict__ X,
    const float* __restrict__ bias, const float* __restrict__ res,
    void* __restrict__ out, ushort* __restrict__ out2, const int K, const int M)
{
  __shared__ __align__(16) char sm[32768];   // A-tile [128][64] @0, X-tile @16384 (xor-swizzled)
  const int tid = threadIdx.x, w = tid >> 6, l = tid & 63;
  const int quad = l >> 4, l15 = l & 15;
  const int n0 = blockIdx.x * 128, m0 = blockIdx.y * 128;
  const int mh = (w & 1) * 64, nh = (w >> 1) * 64;
  const f4 fz = {0.f, 0.f, 0.f, 0.f};
  f4 acc[4][4];
#pragma unroll
  for (int a = 0; a < 4; ++a)
#pragma unroll
    for (int b2 = 0; b2 < 4; ++b2) acc[a][b2] = fz;

  const int KI = K >> 6;
  for (int kk = 0; kk < KI; ++kk) {
    if (kk) __syncthreads();
    const int k0 = kk << 6;
#pragma unroll
    for (int j = 0; j < 4; ++j) {
      int p = j * 256 + tid, r = p >> 3, c = (p & 7) ^ (r & 7);
      gload16(A + (size_t)(m0 + r) * K + k0 + c * 8, sm + (j * 256 + w * 64) * 16);
    }
#pragma unroll
    for (int j = 0; j < 4; ++j) {
      int p = j * 256 + tid, r = p >> 3, c = (p & 7) ^ (r & 7);
      gload16(X + (size_t)(n0 + r) * K + k0 + c * 8, sm + 16384 + (j * 256 + w * 64) * 16);
    }
    __syncthreads();
#pragma unroll
    for (int ks = 0; ks < 2; ++ks) {
      s8 af[4], bx[4];
#pragma unroll
      for (int mt = 0; mt < 4; ++mt) {
        int rr = mh + mt * 16 + l15;
        af[mt] = *(const s8*)(sm + rr * 128 + (((ks * 4 + quad) ^ (rr & 7)) << 4));
      }
#pragma unroll
      for (int nt = 0; nt < 4; ++nt) {
        int rr = nh + nt * 16 + l15;
        bx[nt] = *(const s8*)(sm + 16384 + rr * 128 + (((ks * 4 + quad) ^ (rr & 7)) << 4));
      }
#pragma unroll
      for (int mt = 0; mt < 4; ++mt)
#pragma unroll
        for (int nt = 0; nt < 4; ++nt)
          acc[mt][nt] = __builtin_amdgcn_mfma_f32_16x16x32_bf16(af[mt], bx[nt], acc[mt][nt], 0, 0, 0);
    }
  }
#pragma unroll
  for (int mt = 0; mt < 4; ++mt) {
#pragma unroll
    for (int nt = 0; nt < 4; ++nt) {
      const int m = m0 + mh + mt * 16 + quad * 4;
      const int n = n0 + nh + nt * 16 + l15;
      f4 bb = *(const f4*)(bias + m);
      f4 v = acc[mt][nt] + bb;
      if constexpr (MODE == 0) {
        u2 st; st.x = pk2(v[0], v[1]); st.y = pk2(v[2], v[3]);
        *(u2*)((ushort*)out + (size_t)n * M + m) = st;
      } else if constexpr (MODE == 1 || MODE == 3) {
        f4 r = *(const f4*)(res + (size_t)n * M + m);
        v += r;
        *(f4*)((float*)out + (size_t)n * M + m) = v;
        if constexpr (MODE == 3) {
          u2 st; st.x = pk2(v[0], v[1]); st.y = pk2(v[2], v[3]);
          *(u2*)(out2 + (size_t)n * M + m) = st;
        }
      } else if constexpr (MODE == 4) {
        f4 r;
#pragma unroll
        for (int i = 0; i < 4; ++i) r[i] = res[(size_t)(m + i) * 65536 + n];
        v += r;
        *(f4*)((float*)out + (size_t)n * M + m) = v;
      } else {
        f4 r = *(const f4*)(res + (size_t)n * M + m);
#pragma unroll
        for (int i = 0; i < 4; ++i)
          ((float*)out)[(size_t)(m + i) * 65536 + n] = v[i] + r[i];
      }
    }
  }
}

// ---------------- 3x3 conv as implicit MFMA GEMM (K=9*128) + bias + exact GELU -> bf16
__global__ __launch_bounds__(256) void conv3_kernel(
    const ushort* __restrict__ A, const ushort* __restrict__ X,
    const float* __restrict__ bias, ushort* __restrict__ out,
    const ushort* __restrict__ zp)
{
  __shared__ __align__(16) char sm[32768];
  const int tid = threadIdx.x, w = tid >> 6, l = tid & 63;
  const int quad = l >> 4, l15 = l & 15;
  const int n0 = blockIdx.x * 128, m0 = blockIdx.y * 128;
  const int mh = (w & 1) * 64, nh = (w >> 1) * 64;
  const f4 fz = {0.f, 0.f, 0.f, 0.f};
  f4 acc[4][4];
#pragma unroll
  for (int a = 0; a < 4; ++a)
#pragma unroll
    for (int b2 = 0; b2 < 4; ++b2) acc[a][b2] = fz;

  for (int kk = 0; kk < 18; ++kk) {
    if (kk) __syncthreads();
    const int tap = kk >> 1, ky = tap / 3, kx = tap - ky * 3;
    const int dn = (ky - 1) * 256 + (kx - 1);
    const int kseg = (kk & 1) << 6;
#pragma unroll
    for (int j = 0; j < 4; ++j) {
      int p = j * 256 + tid, r = p >> 3, c = (p & 7) ^ (r & 7);
      gload16(A + (size_t)(m0 + r) * 1152 + kk * 64 + c * 8, sm + (j * 256 + w * 64) * 16);
    }
#pragma unroll
    for (int j = 0; j < 4; ++j) {
      int p = j * 256 + tid, r = p >> 3, c = (p & 7) ^ (r & 7);
      int nl = n0 + r;
      int ys = (nl >> 8) + ky - 1, xs = (nl & 255) + kx - 1;
      const ushort* gp = ((unsigned)ys < 256u && (unsigned)xs < 256u)
                         ? X + (size_t)(nl + dn) * 128 + kseg + c * 8 : zp;
      gload16(gp, sm + 16384 + (j * 256 + w * 64) * 16);
    }
    __syncthreads();
#pragma unroll
    for (int ks = 0; ks < 2; ++ks) {
      s8 af[4], bx[4];
#pragma unroll
      for (int mt = 0; mt < 4; ++mt) {
        int rr = mh + mt * 16 + l15;
        af[mt] = *(const s8*)(sm + rr * 128 + (((ks * 4 + quad) ^ (rr & 7)) << 4));
      }
#pragma unroll
      for (int nt = 0; nt < 4; ++nt) {
        int rr = nh + nt * 16 + l15;
        bx[nt] = *(const s8*)(sm + 16384 + rr * 128 + (((ks * 4 + quad) ^ (rr & 7)) << 4));
      }
#pragma unroll
      for (int mt = 0; mt < 4; ++mt)
#pragma unroll
        for (int nt = 0; nt < 4; ++nt)
          acc[mt][nt] = __builtin_amdgcn_mfma_f32_16x16x32_bf16(af[mt], bx[nt], acc[mt][nt], 0, 0, 0);
    }
  }
#pragma unroll
  for (int mt = 0; mt < 4; ++mt) {
#pragma unroll
    for (int nt = 0; nt < 4; ++nt) {
      const int m = m0 + mh + mt * 16 + quad * 4;
      const int n = n0 + nh + nt * 16 + l15;
      f4 bb = *(const f4*)(bias + m);
      f4 v = acc[mt][nt] + bb;
      float g0 = 0.5f * v[0] * (1.f + erff(v[0] * 0.70710678118f));
      float g1 = 0.5f * v[1] * (1.f + erff(v[1] * 0.70710678118f));
      float g2 = 0.5f * v[2] * (1.f + erff(v[2] * 0.70710678118f));
      float g3 = 0.5f * v[3] * (1.f + erff(v[3] * 0.70710678118f));
      u2 st; st.x = pk2(g0, g1); st.y = pk2(g2, g3);
      *(u2*)(out + (size_t)n * 256 + m) = st;
    }
  }
}

// ---------------- lean fused window attention: 256 threads (4 waves) --------
// One block per (window, head); wave w owns i-tokens [w*64, w*64+64).
// LDS = 64KB only (K 32K + V^T 32K) -> 2 blocks/CU. X and W fragments come
// from global into registers; Q and P stay in registers via the C->B shuffle
// transform; O stores straight to global. Exactly ONE __syncthreads.
__global__ __launch_bounds__(256, 2) void attn_kernel(
    const ushort* __restrict__ xn, const ushort* __restrict__ wq,
    const ushort* __restrict__ wkv, ushort* __restrict__ ao)
{
  __shared__ __align__(16) char sm[65536];
  char* RK  = sm;          // K  [256 tok][64 d] bf16, 16B-chunk xor-swizzled
  char* RVT = sm + 32768;  // V^T [64 d][256 tok] bf16, xor-swizzled
  const int tid = threadIdx.x, w = tid >> 6, l = tid & 63;
  const int quad = l >> 4, l15 = l & 15;
  const int win = blockIdx.x, head = blockIdx.y;
  const int nbase = ((win >> 4) << 12) + ((win & 15) << 4);
  const f4 fz = {0.f, 0.f, 0.f, 0.f};

  // ---- X fragments for this wave's 64 tokens (A/B frag layouts coincide); reused 3x
  s8 bx[4][4];   // [tok-tile][ks]
#pragma unroll
  for (int nt = 0; nt < 4; ++nt) {
    int tok = w * 64 + nt * 16 + l15;
    const char* rowp = (const char*)(xn + (size_t)(nbase + ((tok >> 4) << 8) + (tok & 15)) * 128);
#pragma unroll
    for (int ks = 0; ks < 4; ++ks)
      bx[nt][ks] = *(const s8*)(rowp + (ks * 4 + quad) * 16);
  }
  const char* wqp = (const char*)(wq + (size_t)head * 64 * 128);
  const char* wkp = (const char*)(wkv + (size_t)head * 64 * 128);
  const char* wvp = (const char*)(wkv + (size_t)(512 + head * 64) * 128);

  // ---- Q projection -> registers in B-frag layout (C->B shuffle transform)
  s8 bq[4][2];
  {
    f4 acc[4][4];
#pragma unroll
    for (int a = 0; a < 4; ++a)
#pragma unroll
      for (int b2 = 0; b2 < 4; ++b2) acc[a][b2] = fz;
#pragma unroll
    for (int ks = 0; ks < 4; ++ks) {
      s8 aw[4];
#pragma unroll
      for (int mt = 0; mt < 4; ++mt)
        aw[mt] = *(const s8*)(wqp + (size_t)(mt * 16 + l15) * 256 + (ks * 4 + quad) * 16);
#pragma unroll
      for (int mt = 0; mt < 4; ++mt)
#pragma unroll
        for (int nt = 0; nt < 4; ++nt)
          acc[mt][nt] = __builtin_amdgcn_mfma_f32_16x16x32_bf16(aw[mt], bx[nt][ks], acc[mt][nt], 0, 0, 0);
    }
    // C layout: lane(quad,l15) holds Q[d=mt*16+quad*4+r][tok]; B-frag needs
    // d = ks2*32+quad*8+j at same tok (l15).  (verified transform, round 3)
#pragma unroll
    for (int nt = 0; nt < 4; ++nt) {
      unsigned pd[4][2];
#pragma unroll
      for (int mt = 0; mt < 4; ++mt) {
        pd[mt][0] = pkt(acc[mt][nt][0], acc[mt][nt][1]);
        pd[mt][1] = pkt(acc[mt][nt][2], acc[mt][nt][3]);
      }
#pragma unroll
      for (int ks2 = 0; ks2 < 2; ++ks2) {
        u4v t;
#pragma unroll
        for (int dj = 0; dj < 4; ++dj) {
          int srcl = l15 + (((quad & 1) * 2 + (dj >> 1)) << 4);
          unsigned va = (unsigned)__shfl((int)pd[2 * ks2][dj & 1], srcl, 64);
          unsigned vb = (unsigned)__shfl((int)pd[2 * ks2 + 1][dj & 1], srcl, 64);
          t[dj] = (quad < 2) ? va : vb;
        }
        bq[nt][ks2] = __builtin_bit_cast(s8, t);
      }
    }
  }

  // ---- K projection -> RK [tok][64 d]
  {
    f4 acc[4][4];
#pragma unroll
    for (int a = 0; a < 4; ++a)
#pragma unroll
      for (int b2 = 0; b2 < 4; ++b2) acc[a][b2] = fz;
#pragma unroll
    for (int ks = 0; ks < 4; ++ks) {
      s8 aw[4];
#pragma unroll
      for (int mt = 0; mt < 4; ++mt)
        aw[mt] = *(const s8*)(wkp + (size_t)(mt * 16 + l15) * 256 + (ks * 4 + quad) * 16);
#pragma unroll
      for (int mt = 0; mt < 4; ++mt)
#pragma unroll
        for (int nt = 0; nt < 4; ++nt)
          acc[mt][nt] = __builtin_amdgcn_mfma_f32_16x16x32_bf16(aw[mt], bx[nt][ks], acc[mt][nt], 0, 0, 0);
    }
#pragma unroll
    for (int mt = 0; mt < 4; ++mt)
#pragma unroll
      for (int nt = 0; nt < 4; ++nt) {
        int tok = w * 64 + nt * 16 + l15, d0 = mt * 16 + quad * 4;
        char* a = RK + tok * 128 + (((d0 >> 3) ^ (tok & 7)) << 4) + (d0 & 7) * 2;
        *(unsigned int*)a = pkt(acc[mt][nt][0], acc[mt][nt][1]);
        *(unsigned int*)(a + 4) = pkt(acc[mt][nt][2], acc[mt][nt][3]);
      }
  }

  // ---- V projection (A = X tokens, B = Wv) -> RVT [d][256 tok]
  {
    f4 acc[4][4];
#pragma unroll
    for (int a = 0; a < 4; ++a)
#pragma unroll
      for (int b2 = 0; b2 < 4; ++b2) acc[a][b2] = fz;
#pragma unroll
    for (int ks = 0; ks < 4; ++ks) {
      s8 bw[4];
#pragma unroll
      for (int nt = 0; nt < 4; ++nt)
        bw[nt] = *(const s8*)(wvp + (size_t)(nt * 16 + l15) * 256 + (ks * 4 + quad) * 16);
#pragma unroll
      for (int mt = 0; mt < 4; ++mt)
#pragma unroll
        for (int nt = 0; nt < 4; ++nt)
          acc[mt][nt] = __builtin_amdgcn_mfma_f32_16x16x32_bf16(bx[mt][ks], bw[nt], acc[mt][nt], 0, 0, 0);
    }
#pragma unroll
    for (int mt = 0; mt < 4; ++mt)
#pragma unroll
      for (int nt = 0; nt < 4; ++nt) {
        int d = nt * 16 + l15, t0 = w * 64 + mt * 16 + quad * 4;
        char* a = RVT + d * 512 + (((t0 >> 3) ^ (d & 31)) << 4) + (t0 & 7) * 2;
        *(unsigned int*)a = pkt(acc[mt][nt][0], acc[mt][nt][1]);
        *(unsigned int*)(a + 4) = pkt(acc[mt][nt][2], acc[mt][nt][3]);
      }
  }
  __syncthreads();   // the only barrier: K + V^T visible to all waves

  // ---- flash: S^T = K.Q^T, P = exp2(S*c) (regs), O^T += V^T.P
  f4 o[4][4];
  float lsum[4] = {0.f, 0.f, 0.f, 0.f};
#pragma unroll
  for (int a = 0; a < 4; ++a)
#pragma unroll
    for (int b2 = 0; b2 < 4; ++b2) o[a][b2] = fz;

  for (int jt = 0; jt < 4; ++jt) {
    f4 s[4][4];
#pragma unroll
    for (int a = 0; a < 4; ++a)
#pragma unroll
      for (int b2 = 0; b2 < 4; ++b2) s[a][b2] = fz;
#pragma unroll
    for (int ks2 = 0; ks2 < 2; ++ks2) {
      s8 af[4];
#pragma unroll
      for (int mt = 0; mt < 4; ++mt) {
        int rr = jt * 64 + mt * 16 + l15;
        af[mt] = *(const s8*)(RK + rr * 128 + (((ks2 * 4 + quad) ^ (rr & 7)) << 4));
      }
#pragma unroll
      for (int mt = 0; mt < 4; ++mt)
#pragma unroll
        for (int nt = 0; nt < 4; ++nt)
          s[mt][nt] = __builtin_amdgcn_mfma_f32_16x16x32_bf16(af[mt], bq[nt][ks2], s[mt][nt], 0, 0, 0);
    }
    // P = exp2(S * scale*log2e) -> B-frag registers via the same C->B transform
    s8 Pt[4][2];
#pragma unroll
    for (int nt = 0; nt < 4; ++nt) {
      unsigned pd[4][2];
#pragma unroll
      for (int mt = 0; mt < 4; ++mt) {
        float e0 = exp2f(s[mt][nt][0] * 0.18033688f);
        float e1 = exp2f(s[mt][nt][1] * 0.18033688f);
        float e2 = exp2f(s[mt][nt][2] * 0.18033688f);
        float e3 = exp2f(s[mt][nt][3] * 0.18033688f);
        lsum[nt] += e0 + e1 + e2 + e3;
        pd[mt][0] = pkt(e0, e1);
        pd[mt][1] = pkt(e2, e3);
      }
#pragma unroll
      for (int ks2 = 0; ks2 < 2; ++ks2) {
        u4v t;
#pragma unroll
        for (int dj = 0; dj < 4; ++dj) {
          int srcl = l15 + (((quad & 1) * 2 + (dj >> 1)) << 4);
          unsigned va = (unsigned)__shfl((int)pd[2 * ks2][dj & 1], srcl, 64);
          unsigned vb = (unsigned)__shfl((int)pd[2 * ks2 + 1][dj & 1], srcl, 64);
          t[dj] = (quad < 2) ? va : vb;
        }
        Pt[nt][ks2] = __builtin_bit_cast(s8, t);
      }
    }
#pragma unroll
    for (int ks2 = 0; ks2 < 2; ++ks2) {
      s8 av[4];
#pragma unroll
      for (int mt = 0; mt < 4; ++mt) {
        int d = mt * 16 + l15;
        av[mt] = *(const s8*)(RVT + d * 512 + (((jt * 8 + ks2 * 4 + quad) ^ (d & 31)) << 4));
      }
#pragma unroll
      for (int mt = 0; mt < 4; ++mt)
#pragma unroll
        for (int nt = 0; nt < 4; ++nt)
          o[mt][nt] = __builtin_amdgcn_mfma_f32_16x16x32_bf16(av[mt], Pt[nt][ks2], o[mt][nt], 0, 0, 0);
    }
  }

  // reduce l across quads (j-partials live in quads), then store O directly
  float inv[4];
#pragma unroll
  for (int nt = 0; nt < 4; ++nt) {
    float v = lsum[nt];
    v += __shfl_xor(v, 16, 64);
    v += __shfl_xor(v, 32, 64);
    inv[nt] = 1.f / v;
  }
#pragma unroll
  for (int nt = 0; nt < 4; ++nt) {
    int i = w * 64 + nt * 16 + l15;
    int n = nbase + ((i >> 4) << 8) + (i & 15);
    ushort* dst = ao + (size_t)n * 512 + head * 64 + quad * 4;
#pragma unroll
    for (int mt = 0; mt < 4; ++mt) {
      u2 st;
      st.x = pkt(o[mt][nt][0] * inv[nt], o[mt][nt][1] * inv[nt]);
      st.y = pkt(o[mt][nt][2] * inv[nt], o[mt][nt][3] * inv[nt]);
      *(u2*)(dst + mt * 16) = st;
    }
  }
}

// ---------------------------------------------------------------------------
extern "C" void kernel_launch(void* const* d_in, const int* in_sizes, int n_in,
                              void* d_out, int out_size, void* d_ws, size_t ws_size,
                              hipStream_t stream)
{
  const float* x_in    = (const float*)d_in[0];
  const float* ln1_g   = (const float*)d_in[1];
  const float* ln1_b   = (const float*)d_in[2];
  const float* wq      = (const float*)d_in[3];
  const float* wkv     = (const float*)d_in[4];
  const float* wo      = (const float*)d_in[5];
  const float* bo      = (const float*)d_in[6];
  const float* ln2_g   = (const float*)d_in[7];
  const float* ln2_b   = (const float*)d_in[8];
  const float* w_in    = (const float*)d_in[9];
  const float* b_in    = (const float*)d_in[10];
  const float* w_c3    = (const float*)d_in[11];
  const float* b_c3    = (const float*)d_in[12];
  const float* w_c1    = (const float*)d_in[13];
  const float* b_c1    = (const float*)d_in[14];
  const float* w_outer = (const float*)d_in[15];
  const float* b_outer = (const float*)d_in[16];

  char* wsb = (char*)d_ws;
  ushort* CW = (ushort*)wsb;                       // bf16 weights, 2.46 MB
  float*  XH = (float*)(wsb + 4194304);            // 32 MB residual x, NHWC f32
  ushort* XN = (ushort*)(wsb + 37748736);          // 16 MB LN out, NHWC bf16
  ushort* AO = (ushort*)(wsb + 54525952);          // 64 MB attn out [65536][512] bf16
  ushort* H  = (ushort*)(wsb + 121634816);         // 16 MB FFN hidden bf16
  ushort* G  = (ushort*)(wsb + 138412032);         // 32 MB gelu out [65536][256] bf16
  ushort* XB = (ushort*)(wsb + 171966464);         // 16 MB bf16 copy of x

  const ushort* zp = CW + 1228800;
  dim3 b256(256);

  prep_w<<<dim3(4808), b256, 0, stream>>>(wq, wkv, wo, w_in, w_c3, w_c1, w_outer, CW);

  for (int lyr = 0; lyr < 2; ++lyr) {
    const ushort* cwq = CW + lyr * 65536;
    const ushort* cwkv = CW + 131072 + lyr * 131072;
    const ushort* cwo = CW + 393216 + lyr * 65536;
    const ushort* cwin = CW + 524288 + lyr * 16384;
    const ushort* cw3 = CW + 557056 + lyr * 294912;
    const ushort* cwc1 = CW + 1146880 + lyr * 32768;

    if (lyr == 0)
      ln_nhwc<true><<<dim3(256), b256, 0, stream>>>(x_in, ln1_g, ln1_b, XN);
    else
      ln_nhwc<false><<<dim3(256), b256, 0, stream>>>(XH, ln1_g + lyr * 128, ln1_b + lyr * 128, XN);

    attn_kernel<<<dim3(256, 8), dim3(256), 0, stream>>>(XN, cwq, cwkv, AO);

    if (lyr == 0)
      gemm_nhwc<4><<<dim3(512, 1), b256, 0, stream>>>(cwo, AO, bo, x_in, XH, nullptr, 512, 128);
    else
      gemm_nhwc<1><<<dim3(512, 1), b256, 0, stream>>>(cwo, AO, bo + lyr * 128, XH, XH, nullptr, 512, 128);

    ln_nhwc<false><<<dim3(256), b256, 0, stream>>>(XH, ln2_g + lyr * 128, ln2_b + lyr * 128, XN);
    gemm_nhwc<0><<<dim3(512, 1), b256, 0, stream>>>(cwin, XN, b_in + lyr * 128, nullptr, H, nullptr, 128, 128);
    conv3_kernel<<<dim3(512, 2), b256, 0, stream>>>(cw3, H, b_c3 + lyr * 256, G, zp);

    if (lyr == 1)
      gemm_nhwc<3><<<dim3(512, 1), b256, 0, stream>>>(cwc1, G, b_c1 + lyr * 128, XH, XH, XB, 256, 128);
    else
      gemm_nhwc<1><<<dim3(512, 1), b256, 0, stream>>>(cwc1, G, b_c1 + lyr * 128, XH, XH, nullptr, 256, 128);
  }
  gemm_nhwc<2><<<dim3(512, 1), b256, 0, stream>>>(CW + 1212416, XB, b_outer, XH, d_out, nullptr, 128, 128);
}